// Round 4
// baseline (943.205 us; speedup 1.0000x reference)
//
#include <hip/hip_runtime.h>
#include <hip/hip_bf16.h>

#define EPS_BN 1e-5f

constexpr int B  = 2048, F0 = 64, K = 14;
constexpr int C1 = 64,  F1 = 32;
constexpr int C2 = 128, F2 = 16;
constexpr int C3 = 256, F3 = 8;

typedef __attribute__((ext_vector_type(8))) short bf16x8;
typedef __attribute__((ext_vector_type(4))) float f32x4;

__device__ __forceinline__ float bf2f(unsigned short u) {
    union { unsigned int i; float f; } x; x.i = ((unsigned int)u) << 16; return x.f;
}
__device__ __forceinline__ unsigned short f2bf(float f) {
    union { float f; unsigned int i; } x; x.f = f;
    unsigned int r = (x.i + 0x7fffu + ((x.i >> 16) & 1u)) >> 16;
    return (unsigned short)r;
}

// async global->LDS 16B copy. HW: LDS dest = wave-uniform base + lane*16.
// Callers must keep whole waves active with per-lane-consecutive dests.
__device__ __forceinline__ void gl_lds16(const void* g, void* l) {
    __builtin_amdgcn_global_load_lds(
        (const __attribute__((address_space(1))) unsigned int*)g,
        (__attribute__((address_space(3))) unsigned int*)l,
        16, 0, 0);
}

// ---- fold BN into conv1 weights; also zero the 16B pad-source block ----
__global__ void repack_w1(const float* __restrict__ w1, const float* __restrict__ g,
                          const float* __restrict__ bb, const float* __restrict__ m,
                          const float* __restrict__ v, float* __restrict__ w1f,
                          float* __restrict__ t1, float* __restrict__ zbuf) {
    int i = blockIdx.x * 256 + threadIdx.x;
    if (i < 4) zbuf[i] = 0.0f;
    if (i < C1) {
        float s = g[i] * rsqrtf(v[i] + EPS_BN);
        t1[i] = bb[i] - m[i] * s;
    }
    if (i < C1 * 2 * 9) {
        int c = i / 18;
        float s = g[c] * rsqrtf(v[c] + EPS_BN);
        w1f[i] = w1[i] * s;
    }
}

// ---- repack conv weights into MFMA B-fragment layout, bf16, BN-folded ----
// wp[((chunk*COUT + n)*32) + kk] = W[tap][ci][n]*s[n], chunk=tap*(CIN/32)+cc, ci=cc*32+kk
template<int CIN, int COUT>
__global__ void repack_mfma(const float* __restrict__ w, const float* __restrict__ g,
                            const float* __restrict__ bb, const float* __restrict__ m,
                            const float* __restrict__ v, unsigned short* __restrict__ wp,
                            float* __restrict__ t) {
    int idx = blockIdx.x * 256 + threadIdx.x;
    if (idx < COUT) {
        float s = g[idx] * rsqrtf(v[idx] + EPS_BN);
        t[idx] = bb[idx] - m[idx] * s;
    }
    if (idx < 9 * CIN * COUT) {
        constexpr int CCS = CIN / 32;
        int kk = idx & 31;
        int rest = idx >> 5;
        int n = rest & (COUT - 1);
        int chunk = rest / COUT;
        int tap = chunk / CCS;
        int cc  = chunk & (CCS - 1);
        int ci = cc * 32 + kk;
        float s = g[n] * rsqrtf(v[n] + EPS_BN);
        wp[idx] = f2bf(w[(n * CIN + ci) * 9 + tap] * s);
    }
}

// ---- conv1 (2->64, 3x3, stride (2,1), pad 1) + BN + ReLU, NHWC bf16 out ----
__global__ void conv1_kernel(const float* __restrict__ x, const float* __restrict__ sig,
                             const float* __restrict__ w1f, const float* __restrict__ t1,
                             unsigned short* __restrict__ h1) {
    __shared__ float xs[F0 * K], ssg[F0 * K], wsh[C1 * 19], bsh[C1];
    int b = blockIdx.x, t = threadIdx.x;
    for (int i = t; i < F0 * K; i += 256) {
        xs[i]  = x[(size_t)b * F0 * K + i];
        ssg[i] = sig[(size_t)b * F0 * K + i] * 10.0f;
    }
    for (int i = t; i < C1 * 18; i += 256) {
        int c = i / 18, r = i % 18;
        wsh[c * 19 + r] = w1f[i];
    }
    if (t < C1) bsh[t] = t1[t];
    __syncthreads();
    int c = t & 63, pg = t >> 6;
    for (int p = pg; p < F1 * K; p += 4) {
        int f = p / K, k = p % K;
        float acc = bsh[c];
        #pragma unroll
        for (int df = 0; df < 3; ++df) {
            int fi = 2 * f + df - 1;
            if (fi < 0 || fi >= F0) continue;
            #pragma unroll
            for (int dk = 0; dk < 3; ++dk) {
                int ki = k + dk - 1;
                if (ki < 0 || ki >= K) continue;
                acc = fmaf(xs[fi * K + ki],  wsh[c * 19 + df * 3 + dk], acc);
                acc = fmaf(ssg[fi * K + ki], wsh[c * 19 + 9 + df * 3 + dk], acc);
            }
        }
        h1[(((size_t)b * F1 + f) * K + k) * C1 + c] = f2bf(fmaxf(acc, 0.f));
    }
}

// ---- conv2/conv3 as MFMA GEMM, v5: by-fi planes + G=8, low arch-VGPR ----
// v4 post-mortem: acc[8][NT] (128 AGPR) left only 128 arch VGPRs at MINW=2;
// explicit bA/bB double-buffer + fully-unrolled staging blew past that ->
// scratch spills (FETCH 397MB / WRITE 757MB). v5 keeps the halved weight
// stream (G=8, by-fi planes) but minimizes arch pressure: single bv[NT]
// buffer (compiler pipelines across the unrolled it-loop on its own, as
// proven in round 2), av[4] reused over two g0 passes, staging loop
// unrolled only 4x. Estimated arch ~90 <= 128.
template<int CIN, int COUT, int FIN, int G, int MINW>
__launch_bounds__(256, MINW)
__global__ void conv_mfma(const unsigned short* __restrict__ hin,
                          const unsigned short* __restrict__ wp,
                          const float* __restrict__ tb,
                          const unsigned short* __restrict__ zero16,
                          unsigned short* __restrict__ hout) {
    constexpr int CHW = CIN / 8;             // 16B chunks per row
    constexpr int LOGC = (CHW == 16) ? 4 : 3;
    constexpr int NP = 2 * G + 1;            // fi planes: pf = 2g+df in [0, 2G]
    constexpr int NT = COUT / 64;
    constexpr int CCS = CIN / 32;
    constexpr int NIT = 9 * CCS;             // it == weight chunk index
    __shared__ alignas(16) unsigned short lin[NP * 16 * CIN];

    const int b = blockIdx.y;
    const int f2base = blockIdx.x * G;
    const int t = threadIdx.x;

    // async stage: plane pf, row p (kin=p-1), chunk c8 pre-swizzled (c8^(p&7)).
    // Pad rows (p=0/15, fi=-1) pull from zeroed global block; whole waves stay
    // active (TOT is a multiple of 64), per-lane-consecutive LDS dests.
    constexpr int TOT = NP * 16 * CHW;
    #pragma unroll 4
    for (int i = t; i < TOT; i += 256) {
        int c8 = i & (CHW - 1);
        int row = i >> LOGC;
        int p = row & 15;
        int pf = row >> 4;
        int kin = p - 1;
        int fi = 2 * f2base + pf - 1;        // fi <= 2*(f2base+G)-1 < FIN
        bool valid = (kin >= 0) & (kin < K) & (fi >= 0);
        const unsigned short* src = valid
            ? hin + (((size_t)(b * FIN + fi)) * K + kin) * CIN + ((c8 ^ (p & 7)) << 3)
            : zero16;
        gl_lds16(src, &lin[i * 8]);
    }
    __syncthreads();

    const int lane = t & 63;
    const int wave = t >> 6;
    const int m = lane & 15;                 // A row / B col / D col
    const int quad = lane >> 4;
    const int nBase = wave * (COUT / 4);

    f32x4 acc[G][NT];
    #pragma unroll
    for (int nt = 0; nt < NT; ++nt) {
        float bias = tb[nBase + nt * 16 + m];
        #pragma unroll
        for (int g = 0; g < G; ++g)
            acc[g][nt] = f32x4{bias, bias, bias, bias};
    }

    bf16x8 av[4], bv[NT];
    #pragma unroll
    for (int it = 0; it < NIT; ++it) {
        const int df = it / (3 * CCS), dk = (it / CCS) % 3, cc = it % CCS;
        int p = m + dk; p = (p > 15) ? 15 : p;           // clamp -> zero pad row
        const int cidx = (((cc * 4 + quad) ^ (p & 7)) << 3);
        // weight fragments for this chunk (uniform base + per-lane offset,
        // nt unrolls into immediate offsets)
        #pragma unroll
        for (int nt = 0; nt < NT; ++nt)
            bv[nt] = *(const bf16x8*)(wp + (((it * COUT + nBase + nt * 16 + m)) << 5) + quad * 8);
        #pragma unroll
        for (int g0 = 0; g0 < G; g0 += 4) {
            #pragma unroll
            for (int g = 0; g < 4; ++g)
                av[g] = *(const bf16x8*)&lin[((2 * (g0 + g) + df) * 16 + p) * CIN + cidx];
            #pragma unroll
            for (int g = 0; g < 4; ++g)
                #pragma unroll
                for (int nt = 0; nt < NT; ++nt)
                    acc[g0 + g][nt] = __builtin_amdgcn_mfma_f32_16x16x32_bf16(av[g], bv[nt], acc[g0 + g][nt], 0, 0, 0);
        }
    }

    // epilogue: D[row=quad*4+i][col=m], ReLU, bf16 NHWC store; rows 14,15 = pad
    #pragma unroll
    for (int g = 0; g < G; ++g) {
        size_t rowbase = ((size_t)(b * (FIN / 2) + f2base + g)) * K;
        #pragma unroll
        for (int nt = 0; nt < NT; ++nt) {
            int col = nBase + nt * 16 + m;
            #pragma unroll
            for (int i = 0; i < 4; ++i) {
                int row = quad * 4 + i;
                if (row < K)
                    hout[(rowbase + row) * COUT + col] = f2bf(fmaxf(acc[g][nt][i], 0.f));
            }
        }
    }
}

// ---- conv4 (256->2, kernel (8,1)) + transpose to [B,K,2], vectorized ----
// thread = (c32, f): 8 channels x 1 frame; bf16x8 loads (16B/lane, coalesced
// 512B per (f,k) row across the 32 c32 lanes).
__global__ void conv4_kernel(const unsigned short* __restrict__ h3,
                             const float* __restrict__ w4, float* __restrict__ out) {
    int b = blockIdx.x;
    int t = threadIdx.x;              // 256
    int c32 = t & 31;                 // channel chunk of 8
    int f = t >> 5;                   // frame 0..7
    int c0 = c32 * 8;
    float wa[8], wb[8];
    #pragma unroll
    for (int j = 0; j < 8; ++j) {
        wa[j] = w4[((0 * C3) + c0 + j) * 8 + f];
        wb[j] = w4[((1 * C3) + c0 + j) * 8 + f];
    }
    const unsigned short* base = h3 + ((size_t)(b * F3 + f) * K) * C3 + c0;
    float p0[K], p1[K];
    #pragma unroll
    for (int k = 0; k < K; ++k) {
        bf16x8 v = *(const bf16x8*)(base + k * C3);
        float s0 = 0.f, s1 = 0.f;
        #pragma unroll
        for (int j = 0; j < 8; ++j) {
            float xv = bf2f((unsigned short)v[j]);
            s0 = fmaf(xv, wa[j], s0);
            s1 = fmaf(xv, wb[j], s1);
        }
        p0[k] = s0; p1[k] = s1;
    }
    // reduce over the 32 c32 lanes (width-32 segments; f constant per segment)
    #pragma unroll
    for (int k = 0; k < K; ++k) {
        #pragma unroll
        for (int off = 16; off > 0; off >>= 1) {
            p0[k] += __shfl_down(p0[k], off, 32);
            p1[k] += __shfl_down(p1[k], off, 32);
        }
    }
    __shared__ float red[F3][2 * K];
    if (c32 == 0) {
        #pragma unroll
        for (int k = 0; k < K; ++k) {
            red[f][2 * k + 0] = p0[k];
            red[f][2 * k + 1] = p1[k];
        }
    }
    __syncthreads();
    if (t < 2 * K) {
        float s = 0.f;
        #pragma unroll
        for (int ff = 0; ff < F3; ++ff) s += red[ff][t];
        out[b * (2 * K) + t] = s;
    }
}

extern "C" void kernel_launch(void* const* d_in, const int* in_sizes, int n_in,
                              void* d_out, int out_size, void* d_ws, size_t ws_size,
                              hipStream_t stream) {
    const float* x   = (const float*)d_in[0];
    const float* sig = (const float*)d_in[1];
    const float* w1  = (const float*)d_in[2];
    const float* w2  = (const float*)d_in[3];
    const float* w3  = (const float*)d_in[4];
    const float* w4  = (const float*)d_in[5];
    const float* g1  = (const float*)d_in[6];
    const float* b1  = (const float*)d_in[7];
    const float* m1  = (const float*)d_in[8];
    const float* v1  = (const float*)d_in[9];
    const float* g2  = (const float*)d_in[10];
    const float* b2  = (const float*)d_in[11];
    const float* m2  = (const float*)d_in[12];
    const float* v2  = (const float*)d_in[13];
    const float* g3  = (const float*)d_in[14];
    const float* b3  = (const float*)d_in[15];
    const float* m3  = (const float*)d_in[16];
    const float* v3  = (const float*)d_in[17];

    char* ws = (char*)d_ws;
    size_t off = 0;
    auto alloc = [&](size_t bytes) {
        char* p = ws + off;
        off += (bytes + 255) & ~(size_t)255;
        return p;
    };
    unsigned short* h1  = (unsigned short*)alloc((size_t)B * F1 * K * C1 * 2);  // reused as h3
    unsigned short* h2  = (unsigned short*)alloc((size_t)B * F2 * K * C2 * 2);
    float* w1f = (float*)alloc((size_t)C1 * 2 * 9 * 4);
    float* t1  = (float*)alloc((size_t)C1 * 4);
    unsigned short* wp2 = (unsigned short*)alloc((size_t)9 * C1 * C2 * 2);
    float* t2  = (float*)alloc((size_t)C2 * 4);
    unsigned short* wp3 = (unsigned short*)alloc((size_t)9 * C2 * C3 * 2);
    float* t3  = (float*)alloc((size_t)C3 * 4);
    float* zbuf = (float*)alloc(16);
    unsigned short* h3 = h1;

    repack_w1<<<(C1 * 2 * 9 + 255) / 256, 256, 0, stream>>>(w1, g1, b1, m1, v1, w1f, t1, zbuf);
    repack_mfma<C1, C2><<<(9 * C1 * C2 + 255) / 256, 256, 0, stream>>>(w2, g2, b2, m2, v2, wp2, t2);
    repack_mfma<C2, C3><<<(9 * C2 * C3 + 255) / 256, 256, 0, stream>>>(w3, g3, b3, m3, v3, wp3, t3);

    conv1_kernel<<<B, 256, 0, stream>>>(x, sig, w1f, t1, h1);
    // conv2: 64->128, 16 output frames, G=8 -> grid (2, B); acc=64 AGPR, MINW=3
    conv_mfma<C1, C2, F1, 8, 3><<<dim3(F1 / 2 / 8, B), 256, 0, stream>>>(h1, wp2, t2, (const unsigned short*)zbuf, h2);
    // conv3: 128->256, 8 output frames, G=8 -> grid (1, B); acc=128 AGPR, MINW=2
    conv_mfma<C2, C3, F2, 8, 2><<<dim3(F2 / 2 / 8, B), 256, 0, stream>>>(h2, wp3, t3, (const unsigned short*)zbuf, h3);
    conv4_kernel<<<B, 256, 0, stream>>>(h3, w4, (float*)d_out);
}

// Round 5
// 527.689 us; speedup vs baseline: 1.7874x; 1.7874x over previous
//
#include <hip/hip_runtime.h>
#include <hip/hip_bf16.h>

#define EPS_BN 1e-5f

constexpr int B  = 2048, F0 = 64, K = 14;
constexpr int C1 = 64,  F1 = 32;
constexpr int C2 = 128, F2 = 16;
constexpr int C3 = 256, F3 = 8;

typedef __attribute__((ext_vector_type(8))) short bf16x8;
typedef __attribute__((ext_vector_type(4))) float f32x4;

__device__ __forceinline__ float bf2f(unsigned short u) {
    union { unsigned int i; float f; } x; x.i = ((unsigned int)u) << 16; return x.f;
}
__device__ __forceinline__ unsigned short f2bf(float f) {
    union { float f; unsigned int i; } x; x.f = f;
    unsigned int r = (x.i + 0x7fffu + ((x.i >> 16) & 1u)) >> 16;
    return (unsigned short)r;
}

// async global->LDS 16B copy. HW: LDS dest = wave-uniform base + lane*16.
// Callers must keep whole waves active with per-lane-consecutive dests.
__device__ __forceinline__ void gl_lds16(const void* g, void* l) {
    __builtin_amdgcn_global_load_lds(
        (const __attribute__((address_space(1))) unsigned int*)g,
        (__attribute__((address_space(3))) unsigned int*)l,
        16, 0, 0);
}

// ---- fold BN into conv1 weights; also zero the 16B pad-source block ----
__global__ void repack_w1(const float* __restrict__ w1, const float* __restrict__ g,
                          const float* __restrict__ bb, const float* __restrict__ m,
                          const float* __restrict__ v, float* __restrict__ w1f,
                          float* __restrict__ t1, float* __restrict__ zbuf) {
    int i = blockIdx.x * 256 + threadIdx.x;
    if (i < 4) zbuf[i] = 0.0f;
    if (i < C1) {
        float s = g[i] * rsqrtf(v[i] + EPS_BN);
        t1[i] = bb[i] - m[i] * s;
    }
    if (i < C1 * 2 * 9) {
        int c = i / 18;
        float s = g[c] * rsqrtf(v[c] + EPS_BN);
        w1f[i] = w1[i] * s;
    }
}

// ---- repack conv weights into MFMA B-fragment layout, bf16, BN-folded ----
// wp[((chunk*COUT + n)*32) + kk] = W[tap][ci][n]*s[n], chunk=tap*(CIN/32)+cc, ci=cc*32+kk
template<int CIN, int COUT>
__global__ void repack_mfma(const float* __restrict__ w, const float* __restrict__ g,
                            const float* __restrict__ bb, const float* __restrict__ m,
                            const float* __restrict__ v, unsigned short* __restrict__ wp,
                            float* __restrict__ t) {
    int idx = blockIdx.x * 256 + threadIdx.x;
    if (idx < COUT) {
        float s = g[idx] * rsqrtf(v[idx] + EPS_BN);
        t[idx] = bb[idx] - m[idx] * s;
    }
    if (idx < 9 * CIN * COUT) {
        constexpr int CCS = CIN / 32;
        int kk = idx & 31;
        int rest = idx >> 5;
        int n = rest & (COUT - 1);
        int chunk = rest / COUT;
        int tap = chunk / CCS;
        int cc  = chunk & (CCS - 1);
        int ci = cc * 32 + kk;
        float s = g[n] * rsqrtf(v[n] + EPS_BN);
        wp[idx] = f2bf(w[(n * CIN + ci) * 9 + tap] * s);
    }
}

// ---- conv1 (2->64, 3x3, stride (2,1), pad 1) + BN + ReLU, NHWC bf16 out ----
__global__ void conv1_kernel(const float* __restrict__ x, const float* __restrict__ sig,
                             const float* __restrict__ w1f, const float* __restrict__ t1,
                             unsigned short* __restrict__ h1) {
    __shared__ float xs[F0 * K], ssg[F0 * K], wsh[C1 * 19], bsh[C1];
    int b = blockIdx.x, t = threadIdx.x;
    for (int i = t; i < F0 * K; i += 256) {
        xs[i]  = x[(size_t)b * F0 * K + i];
        ssg[i] = sig[(size_t)b * F0 * K + i] * 10.0f;
    }
    for (int i = t; i < C1 * 18; i += 256) {
        int c = i / 18, r = i % 18;
        wsh[c * 19 + r] = w1f[i];
    }
    if (t < C1) bsh[t] = t1[t];
    __syncthreads();
    int c = t & 63, pg = t >> 6;
    for (int p = pg; p < F1 * K; p += 4) {
        int f = p / K, k = p % K;
        float acc = bsh[c];
        #pragma unroll
        for (int df = 0; df < 3; ++df) {
            int fi = 2 * f + df - 1;
            if (fi < 0 || fi >= F0) continue;
            #pragma unroll
            for (int dk = 0; dk < 3; ++dk) {
                int ki = k + dk - 1;
                if (ki < 0 || ki >= K) continue;
                acc = fmaf(xs[fi * K + ki],  wsh[c * 19 + df * 3 + dk], acc);
                acc = fmaf(ssg[fi * K + ki], wsh[c * 19 + 9 + df * 3 + dk], acc);
            }
        }
        h1[(((size_t)b * F1 + f) * K + k) * C1 + c] = f2bf(fmaxf(acc, 0.f));
    }
}

// ---- conv2/conv3 as MFMA GEMM, v6: G=4 + 2-phase LDS weight pipeline ----
// v4/v5 post-mortem: G=8 needs 128 accumulator regs -> allocator caps arch
// VGPR at 128 and spills everything else (WRITE 888MB scratch). Revert to the
// proven G=4 shape (round 2: 76 VGPR, no spill) and instead attack the
// EXPOSED per-iteration weight-load latency (compiler sinks global loads to
// just-before-use; ~250cy L2 latency serial per it-step -> MfmaUtil 34%).
// Fix: double-buffered weight chunks staged LDS-side via global_load_lds
// (async DMA, zero VGPR cost). Per phase: issue stage(it+1 -> other buf),
// compute it from LDS, __syncthreads (its vmcnt(0) drain lands AFTER the
// 16-MFMA compute, so the DMA has the whole phase to complete).
// Weight LDS reads are row-per-lane strided (T2 pattern) -> XOR chunk
// swizzle q^=(n&3) on both DMA source and ds_read (rule 21).
template<int CIN, int COUT, int FIN, int G, int MINW>
__launch_bounds__(256, MINW)
__global__ void conv_mfma(const unsigned short* __restrict__ hin,
                          const unsigned short* __restrict__ wp,
                          const float* __restrict__ tb,
                          const unsigned short* __restrict__ zero16,
                          unsigned short* __restrict__ hout) {
    constexpr int CHW = CIN / 8;             // 16B chunks per input row
    constexpr int LOGC = (CHW == 16) ? 4 : 3;
    constexpr int NP = 2 * G + 1;            // fi planes: pf = 2g+df in [0, 2G]
    constexpr int NT = COUT / 64;
    constexpr int CCS = CIN / 32;
    constexpr int NIT = 9 * CCS;             // weight chunk count (18 / 36), even
    constexpr int WCH = COUT * 4;            // 16B chunks per weight k-block
    __shared__ alignas(16) unsigned short lin[NP * 16 * CIN];
    __shared__ alignas(16) unsigned short wl0[COUT * 32];
    __shared__ alignas(16) unsigned short wl1[COUT * 32];

    const int b = blockIdx.y;
    const int f2base = blockIdx.x * G;
    const int t = threadIdx.x;

    // ---- async input stage: plane pf, row p (kin=p-1), chunk c8^(p&7) ----
    // Pad rows (p=0/15, fi=-1) pull from zeroed global block; whole waves
    // stay active (TOT is a multiple of 64), per-lane-consecutive LDS dests.
    constexpr int TOT = NP * 16 * CHW;
    #pragma unroll 4
    for (int i = t; i < TOT; i += 256) {
        int c8 = i & (CHW - 1);
        int row = i >> LOGC;
        int p = row & 15;
        int pf = row >> 4;
        int kin = p - 1;
        int fi = 2 * f2base + pf - 1;        // fi <= 2*(f2base+G)-1 < FIN
        bool valid = (kin >= 0) & (kin < K) & (fi >= 0);
        const unsigned short* src = valid
            ? hin + (((size_t)(b * FIN + fi)) * K + kin) * CIN + ((c8 ^ (p & 7)) << 3)
            : zero16;
        gl_lds16(src, &lin[i * 8]);
    }

    // ---- async weight stage: chunk it -> buffer; LDS slot j=n*4+q holds
    // global chunk (q ^ (n&3)) of weight row n of k-block it ----
    auto stage_w = [&](int it, unsigned short* wb) {
        #pragma unroll
        for (int j = t; j < WCH; j += 256) {
            int n = j >> 2, q = j & 3;
            const unsigned short* src =
                wp + (((size_t)it * COUT + n) << 5) + ((q ^ (n & 3)) << 3);
            gl_lds16(src, &wb[j * 8]);
        }
    };
    stage_w(0, wl0);
    __syncthreads();   // input + first weight chunk resident

    const int lane = t & 63;
    const int wave = t >> 6;
    const int m = lane & 15;                 // A row / B col / D col
    const int quad = lane >> 4;
    const int nBase = wave * (COUT / 4);

    f32x4 acc[G][NT];
    #pragma unroll
    for (int nt = 0; nt < NT; ++nt) {
        float bias = tb[nBase + nt * 16 + m];
        #pragma unroll
        for (int g = 0; g < G; ++g)
            acc[g][nt] = f32x4{bias, bias, bias, bias};
    }

    auto compute = [&](int it, const unsigned short* wb) {
        const int df = it / (3 * CCS), dk = (it / CCS) % 3, cc = it % CCS;
        int p = m + dk; p = (p > 15) ? 15 : p;           // clamp -> zero pad row
        const int cidx = (((cc * 4 + quad) ^ (p & 7)) << 3);
        bf16x8 bv[NT], av[G];
        #pragma unroll
        for (int nt = 0; nt < NT; ++nt) {
            int n = nBase + nt * 16 + m;
            bv[nt] = *(const bf16x8*)&wb[(n * 4 + (quad ^ (n & 3))) * 8];
        }
        #pragma unroll
        for (int g = 0; g < G; ++g)
            av[g] = *(const bf16x8*)&lin[((2 * g + df) * 16 + p) * CIN + cidx];
        #pragma unroll
        for (int g = 0; g < G; ++g)
            #pragma unroll
            for (int nt = 0; nt < NT; ++nt)
                acc[g][nt] = __builtin_amdgcn_mfma_f32_16x16x32_bf16(av[g], bv[nt], acc[g][nt], 0, 0, 0);
    };

    #pragma unroll
    for (int it = 0; it < NIT; it += 2) {
        stage_w(it + 1, wl1);                // async, lands during compute
        compute(it, wl0);
        __syncthreads();                     // drains stage(it+1); wl0 free
        if (it + 2 < NIT) stage_w(it + 2, wl0);
        compute(it + 1, wl1);
        __syncthreads();                     // drains stage(it+2); wl1 free
    }

    // epilogue: D[row=quad*4+i][col=m], ReLU, bf16 NHWC store; rows 14,15 = pad
    #pragma unroll
    for (int g = 0; g < G; ++g) {
        size_t rowbase = ((size_t)(b * (FIN / 2) + f2base + g)) * K;
        #pragma unroll
        for (int nt = 0; nt < NT; ++nt) {
            int col = nBase + nt * 16 + m;
            #pragma unroll
            for (int i = 0; i < 4; ++i) {
                int row = quad * 4 + i;
                if (row < K)
                    hout[(rowbase + row) * COUT + col] = f2bf(fmaxf(acc[g][nt][i], 0.f));
            }
        }
    }
}

// ---- conv4 (256->2, kernel (8,1)) + transpose to [B,K,2], vectorized ----
// thread = (c32, f): 8 channels x 1 frame; bf16x8 loads (16B/lane, coalesced
// 512B per (f,k) row across the 32 c32 lanes).
__global__ void conv4_kernel(const unsigned short* __restrict__ h3,
                             const float* __restrict__ w4, float* __restrict__ out) {
    int b = blockIdx.x;
    int t = threadIdx.x;              // 256
    int c32 = t & 31;                 // channel chunk of 8
    int f = t >> 5;                   // frame 0..7
    int c0 = c32 * 8;
    float wa[8], wb[8];
    #pragma unroll
    for (int j = 0; j < 8; ++j) {
        wa[j] = w4[((0 * C3) + c0 + j) * 8 + f];
        wb[j] = w4[((1 * C3) + c0 + j) * 8 + f];
    }
    const unsigned short* base = h3 + ((size_t)(b * F3 + f) * K) * C3 + c0;
    float p0[K], p1[K];
    #pragma unroll
    for (int k = 0; k < K; ++k) {
        bf16x8 v = *(const bf16x8*)(base + k * C3);
        float s0 = 0.f, s1 = 0.f;
        #pragma unroll
        for (int j = 0; j < 8; ++j) {
            float xv = bf2f((unsigned short)v[j]);
            s0 = fmaf(xv, wa[j], s0);
            s1 = fmaf(xv, wb[j], s1);
        }
        p0[k] = s0; p1[k] = s1;
    }
    // reduce over the 32 c32 lanes (width-32 segments; f constant per segment)
    #pragma unroll
    for (int k = 0; k < K; ++k) {
        #pragma unroll
        for (int off = 16; off > 0; off >>= 1) {
            p0[k] += __shfl_down(p0[k], off, 32);
            p1[k] += __shfl_down(p1[k], off, 32);
        }
    }
    __shared__ float red[F3][2 * K];
    if (c32 == 0) {
        #pragma unroll
        for (int k = 0; k < K; ++k) {
            red[f][2 * k + 0] = p0[k];
            red[f][2 * k + 1] = p1[k];
        }
    }
    __syncthreads();
    if (t < 2 * K) {
        float s = 0.f;
        #pragma unroll
        for (int ff = 0; ff < F3; ++ff) s += red[ff][t];
        out[b * (2 * K) + t] = s;
    }
}

extern "C" void kernel_launch(void* const* d_in, const int* in_sizes, int n_in,
                              void* d_out, int out_size, void* d_ws, size_t ws_size,
                              hipStream_t stream) {
    const float* x   = (const float*)d_in[0];
    const float* sig = (const float*)d_in[1];
    const float* w1  = (const float*)d_in[2];
    const float* w2  = (const float*)d_in[3];
    const float* w3  = (const float*)d_in[4];
    const float* w4  = (const float*)d_in[5];
    const float* g1  = (const float*)d_in[6];
    const float* b1  = (const float*)d_in[7];
    const float* m1  = (const float*)d_in[8];
    const float* v1  = (const float*)d_in[9];
    const float* g2  = (const float*)d_in[10];
    const float* b2  = (const float*)d_in[11];
    const float* m2  = (const float*)d_in[12];
    const float* v2  = (const float*)d_in[13];
    const float* g3  = (const float*)d_in[14];
    const float* b3  = (const float*)d_in[15];
    const float* m3  = (const float*)d_in[16];
    const float* v3  = (const float*)d_in[17];

    char* ws = (char*)d_ws;
    size_t off = 0;
    auto alloc = [&](size_t bytes) {
        char* p = ws + off;
        off += (bytes + 255) & ~(size_t)255;
        return p;
    };
    unsigned short* h1  = (unsigned short*)alloc((size_t)B * F1 * K * C1 * 2);  // reused as h3
    unsigned short* h2  = (unsigned short*)alloc((size_t)B * F2 * K * C2 * 2);
    float* w1f = (float*)alloc((size_t)C1 * 2 * 9 * 4);
    float* t1  = (float*)alloc((size_t)C1 * 4);
    unsigned short* wp2 = (unsigned short*)alloc((size_t)9 * C1 * C2 * 2);
    float* t2  = (float*)alloc((size_t)C2 * 4);
    unsigned short* wp3 = (unsigned short*)alloc((size_t)9 * C2 * C3 * 2);
    float* t3  = (float*)alloc((size_t)C3 * 4);
    float* zbuf = (float*)alloc(16);
    unsigned short* h3 = h1;

    repack_w1<<<(C1 * 2 * 9 + 255) / 256, 256, 0, stream>>>(w1, g1, b1, m1, v1, w1f, t1, zbuf);
    repack_mfma<C1, C2><<<(9 * C1 * C2 + 255) / 256, 256, 0, stream>>>(w2, g2, b2, m2, v2, wp2, t2);
    repack_mfma<C2, C3><<<(9 * C2 * C3 + 255) / 256, 256, 0, stream>>>(w3, g3, b3, m3, v3, wp3, t3);

    conv1_kernel<<<B, 256, 0, stream>>>(x, sig, w1f, t1, h1);
    // conv2: 64->128, 16 output frames, G=4 -> grid (4, B); LDS 34.8KB
    conv_mfma<C1, C2, F1, 4, 3><<<dim3(F1 / 2 / 4, B), 256, 0, stream>>>(h1, wp2, t2, (const unsigned short*)zbuf, h2);
    // conv3: 128->256, 8 output frames, G=4 -> grid (2, B); LDS 68.6KB
    conv_mfma<C2, C3, F2, 4, 2><<<dim3(F2 / 2 / 4, B), 256, 0, stream>>>(h2, wp3, t3, (const unsigned short*)zbuf, h3);
    conv4_kernel<<<B, 256, 0, stream>>>(h3, w4, (float*)d_out);
}